// Round 12
// baseline (162.083 us; speedup 1.0000x reference)
//
#include <hip/hip_runtime.h>
#include <math.h>

// Problem constants (B,K,N,M) = (32,128,128,256)
#define Bb 32
#define Kk 128
#define Nn 128
#define Mm 256
#define EPS2 0.01f      // EPSILON^2
#define LAMBDA_S 0.1f
#define LR 0.01f
#define BN_EPS_C 1e-5f

#define SWZ(c) (((c) & 14) | (((c) & 1) << 4) | (((c) >> 4) & 1))

__device__ __forceinline__ float readlane_f(float v, int lane) {
  return __int_as_float(__builtin_amdgcn_readlane(__float_as_int(v), lane));
}

// ---------------------------------------------------------------------------
// kPre: Psum[e] = sum_k P[k][e]. grid 64, block 256.
__global__ void kPre(const float* __restrict__ P, float* __restrict__ Psum) {
  int e = blockIdx.x * 256 + threadIdx.x;
  float s = 0.f;
  #pragma unroll 8
  for (int k = 0; k < Kk; ++k) s += P[(size_t)k * 16384 + e];
  Psum[e] = s;
}

// ---------------------------------------------------------------------------
// kBig (R19): grid 321, block 512. Independent block roles (block-uniform):
//  bx 0..128   : R11-proven blocked GJ inverse (8 waves, 4x8 reg tiles)
//  bx 129..192 : raw gram R_b = x_b x_b^T halves + rowsums r[b]  (no BN dep)
//  bx 193..320 : BN stats (mean/rstd per n) + write xn  (kA's work, in shadow)
__global__ __launch_bounds__(512, 1) void kBig(
    const float* __restrict__ P, const float* __restrict__ Psum,
    const float* __restrict__ cnt, float* __restrict__ C,
    const float* __restrict__ x, float* __restrict__ R,
    float* __restrict__ rbuf, float* __restrict__ meanB,
    float* __restrict__ rstdB, float* __restrict__ xn) {
  __shared__ __align__(16) float LB[8448];
  int bx = blockIdx.x;
  int t = threadIdx.x;

  if (bx < 129) {
    float* Mt = LB;            // 16*132 = 2112
    float* Rb = LB + 2112;     // 16*128 = 2048
    float* redc = LB + 4160;   // 8
    int mat = bx;
    int tx = t & 15;           // col group (8 cols)
    int wy = t >> 4;           // row group (4 rows), 0..31

    float cv = cnt[t & 127];
    float sr = cv;
    #pragma unroll
    for (int o = 32; o > 0; o >>= 1) sr += __shfl_down(sr, o, 64);
    if ((t & 63) == 0) redc[t >> 6] = sr;
    __syncthreads();
    float total = redc[0] + redc[1];
    bool has = total > 1e-6f;
    float av;
    if (mat < 128) {
      float c = cnt[mat];
      float bk = (c != 0.0f) ? 1.0f : 0.0f;
      float cfix = c + (1.0f - bk);
      av = (float)Nn / (cfix * EPS2) * bk;
    } else {
      av = has ? ((float)Nn / (EPS2 * total)) : 0.0f;
    }
    const float* src = (mat < 128) ? (P + (size_t)mat * 16384) : Psum;

    float a[4][8];
    #pragma unroll
    for (int i = 0; i < 4; ++i) {
      int row = wy * 4 + i;
      float4 p0 = *(const float4*)&src[row * 128 + tx * 8];
      float4 p1 = *(const float4*)&src[row * 128 + tx * 8 + 4];
      a[i][0] = av * p0.x; a[i][1] = av * p0.y; a[i][2] = av * p0.z; a[i][3] = av * p0.w;
      a[i][4] = av * p1.x; a[i][5] = av * p1.y; a[i][6] = av * p1.z; a[i][7] = av * p1.w;
      if (tx == (wy >> 1)) a[i][(wy & 1) * 4 + i] += 1.0f;
    }

    for (int kb = 0; kb < 8; ++kb) {
      int k0 = kb * 16;
      if ((wy >> 2) == kb) {          // R dump (panel rows, swizzled)
        int d = wy & 3;
        #pragma unroll
        for (int i = 0; i < 4; ++i) {
          *(float4*)&Rb[(d * 4 + i) * 128 + SWZ(2 * tx) * 4] =
              make_float4(a[i][0], a[i][1], a[i][2], a[i][3]);
          *(float4*)&Rb[(d * 4 + i) * 128 + SWZ(2 * tx + 1) * 4] =
              make_float4(a[i][4], a[i][5], a[i][6], a[i][7]);
        }
      }
      if ((tx >> 1) == kb) {          // M dump (panel cols, transposed)
        int dh = tx & 1;
        #pragma unroll
        for (int i = 0; i < 4; ++i)
          #pragma unroll
          for (int j = 0; j < 8; ++j)
            Mt[(dh * 8 + j) * 132 + wy * 4 + i] = a[i][j];
      }
      __syncthreads();

      if (t < 64) {                   // wave 0 factors the 128x16 panel
        int l = t;
        float m[2][16];
        #pragma unroll
        for (int d = 0; d < 2; ++d)
          #pragma unroll
          for (int j = 0; j < 16; ++j)
            m[d][j] = Mt[j * 132 + 2 * l + d];
        #pragma unroll
        for (int q = 0; q < 16; ++q) {
          int lq = (k0 + q) >> 1;     // wave-uniform owner lane
          float pr[16];
          #pragma unroll
          for (int j = 0; j < 16; ++j) pr[j] = readlane_f(m[q & 1][j], lq);
          float piv = pr[q];
          float r0 = __builtin_amdgcn_rcpf(piv);
          float pinv = r0 * (2.0f - piv * r0);   // Newton -> ~fp32-exact
          #pragma unroll
          for (int d = 0; d < 2; ++d) {
            float f = m[d][q];
            bool isp = (2 * l + d == k0 + q);
            float g = isp ? (1.0f - pinv) : f * pinv;
            #pragma unroll
            for (int j = 0; j < 16; ++j) m[d][j] = fmaf(-g, pr[j], m[d][j]);
            m[d][q] = isp ? pinv : -g;
          }
        }
        #pragma unroll
        for (int d = 0; d < 2; ++d)
          #pragma unroll
          for (int j = 0; j < 16; ++j)
            Mt[j * 132 + 2 * l + d] = m[d][j];
      }
      __syncthreads();

      if ((wy >> 2) == kb) {          // panel rows restart acc
        #pragma unroll
        for (int i = 0; i < 4; ++i)
          #pragma unroll
          for (int j = 0; j < 8; ++j) a[i][j] = 0.0f;
      }
      #pragma unroll
      for (int q = 0; q < 16; ++q) {
        float4 m0 = *(const float4*)&Mt[q * 132 + wy * 4];
        float4 r0 = *(const float4*)&Rb[q * 128 + SWZ(2 * tx) * 4];
        float4 r1 = *(const float4*)&Rb[q * 128 + SWZ(2 * tx + 1) * 4];
        float mq[4] = {m0.x, m0.y, m0.z, m0.w};
        float rq[8] = {r0.x, r0.y, r0.z, r0.w, r1.x, r1.y, r1.z, r1.w};
        #pragma unroll
        for (int i = 0; i < 4; ++i)
          #pragma unroll
          for (int j = 0; j < 8; ++j)
            a[i][j] = fmaf(mq[i], rq[j], a[i][j]);
      }
      if ((tx >> 1) == kb) {          // panel cols reload M
        int dh = tx & 1;
        #pragma unroll
        for (int j = 0; j < 8; ++j) {
          float4 v0 = *(const float4*)&Mt[(dh * 8 + j) * 132 + wy * 4];
          a[0][j] = v0.x; a[1][j] = v0.y; a[2][j] = v0.z; a[3][j] = v0.w;
        }
      }
      __syncthreads();
    }

    float* dst = C + (size_t)mat * 16384;
    #pragma unroll
    for (int i = 0; i < 4; ++i) {
      int row = wy * 4 + i;
      float4 v0 = make_float4(av * a[i][0], av * a[i][1], av * a[i][2], av * a[i][3]);
      float4 v1 = make_float4(av * a[i][4], av * a[i][5], av * a[i][6], av * a[i][7]);
      *(float4*)&dst[row * 128 + tx * 8] = v0;
      *(float4*)&dst[row * 128 + tx * 8 + 4] = v1;
    }
  } else if (bx < 193) {
    // ---- raw gram branch: R_b = x_b x_b^T (half) + rowsums ----
    int bxx = bx - 129;
    int b = bxx >> 1;
    int jbase = (bxx & 1) * 64;
    float* X = LB;  // 128*65 = 8320 floats
    int tx = t & 15, wy = t >> 4;   // wy 0..31
    float acc[4][4] = {};
    float rsum = 0.f;
    for (int mc = 0; mc < Mm; mc += 64) {
      __syncthreads();
      #pragma unroll
      for (int c = 0; c < 16; ++c) {   // all 512 threads stage
        int e = c * 512 + t;
        int i = e >> 6, mm = e & 63;
        X[i * 65 + mm] = x[(size_t)b * (Nn * Mm) + i * Mm + mc + mm];
      }
      __syncthreads();
      if (t < 128) {                   // rowsums of raw x (waves 0-1)
        #pragma unroll
        for (int mm = 0; mm < 64; ++mm) rsum += X[t * 65 + mm];
      }
      for (int mm = 0; mm < 64; ++mm) {
        float ai[4], bj[4];
        #pragma unroll
        for (int q = 0; q < 4; ++q) ai[q] = X[(wy * 4 + q) * 65 + mm];
        #pragma unroll
        for (int q = 0; q < 4; ++q) bj[q] = X[(jbase + tx * 4 + q) * 65 + mm];
        #pragma unroll
        for (int qi = 0; qi < 4; ++qi)
          #pragma unroll
          for (int qj = 0; qj < 4; ++qj)
            acc[qi][qj] = fmaf(ai[qi], bj[qj], acc[qi][qj]);
      }
    }
    float* dst = R + (size_t)b * 16384;
    #pragma unroll
    for (int qi = 0; qi < 4; ++qi) {
      float4 v = make_float4(acc[qi][0], acc[qi][1], acc[qi][2], acc[qi][3]);
      *(float4*)&dst[(wy * 4 + qi) * 128 + jbase + tx * 4] = v;
    }
    if (jbase == 0 && t < 128) rbuf[b * 128 + t] = rsum;
  } else {
    // ---- BN branch: stats for n = bx-193 over (B,M) AND write xn ----
    int n = bx - 193;
    int m = t & 255, bh = t >> 8;     // bh in {0,1}: 16 b's each
    float v[16];
    float s = 0.f, s2 = 0.f;
    #pragma unroll
    for (int q = 0; q < 16; ++q) {
      v[q] = x[(size_t)(bh * 16 + q) * (Nn * Mm) + n * Mm + m];
      s += v[q]; s2 += v[q] * v[q];
    }
    #pragma unroll
    for (int o = 32; o > 0; o >>= 1) {
      s += __shfl_down(s, o, 64);
      s2 += __shfl_down(s2, o, 64);
    }
    if ((t & 63) == 0) { LB[t >> 6] = s; LB[16 + (t >> 6)] = s2; }
    __syncthreads();
    float S = 0.f, S2 = 0.f;
    #pragma unroll
    for (int w = 0; w < 8; ++w) { S += LB[w]; S2 += LB[16 + w]; }
    float mean = S * (1.0f / (Bb * Mm));
    float var = S2 * (1.0f / (Bb * Mm)) - mean * mean;
    float rstd = 1.0f / sqrtf(var + BN_EPS_C);
    if (t == 0) { meanB[n] = mean; rstdB[n] = rstd; }
    #pragma unroll
    for (int q = 0; q < 16; ++q)
      xn[(size_t)(bh * 16 + q) * (Nn * Mm) + n * Mm + m] = (v[q] - mean) * rstd;
  }
}

// ---------------------------------------------------------------------------
// kGN (R15-proven): grid 512 = (k, j-quarter). Ghat gram + <Ghat,R_b> + BN
// correction: norm2(b,k) = <Ghat,R_b> - 2 u.r_b + 256 mu.u,  u = Ghat mu.
__global__ __launch_bounds__(256, 1) void kGN(const float* __restrict__ C,
                                              const float* __restrict__ R,
                                              const float* __restrict__ rbuf,
                                              const float* __restrict__ meanB,
                                              const float* __restrict__ rstdB,
                                              float* __restrict__ norm2h) {
  __shared__ __align__(16) float LB[128 * 128];  // 64 KB
  __shared__ float redb[4][32];
  __shared__ float muL[128], rsL[128], uL[128];
  int k = blockIdx.x >> 2, qh = blockIdx.x & 3;
  int t = threadIdx.x;
  if (t < 128) { muL[t] = meanB[t]; rsL[t] = rstdB[t]; }
  const float* src = C + (size_t)k * 16384;
  for (int c = 0; c < 64; ++c) LB[c * 256 + t] = src[c * 256 + t];
  __syncthreads();
  int tx = t & 15, ty = t >> 4;
  int i0 = ty * 8, j0 = qh * 32 + tx * 2;
  float acc[8][2] = {};
  #pragma unroll 2
  for (int l = 0; l < 128; ++l) {
    float ai[8];
    *(float4*)&ai[0] = *(const float4*)&LB[l * 128 + i0];
    *(float4*)&ai[4] = *(const float4*)&LB[l * 128 + i0 + 4];
    float2 bj = *(const float2*)&LB[l * 128 + j0];
    #pragma unroll
    for (int qi = 0; qi < 8; ++qi) {
      acc[qi][0] = fmaf(ai[qi], bj.x, acc[qi][0]);
      acc[qi][1] = fmaf(ai[qi], bj.y, acc[qi][1]);
    }
  }
  __syncthreads();
  float sj0 = rsL[j0], sj1 = rsL[j0 + 1];
  #pragma unroll
  for (int qi = 0; qi < 8; ++qi) {
    float si = rsL[i0 + qi];
    *(float2*)&LB[(i0 + qi) * 32 + tx * 2] =
        make_float2(acc[qi][0] * si * sj0, acc[qi][1] * si * sj1);
  }
  __syncthreads();
  if (t < 128) {                     // u_q[i] = sum_{j in quarter} Ghat[i][j] mu_j
    float u = 0.f;
    #pragma unroll
    for (int jl = 0; jl < 32; ++jl)
      u = fmaf(LB[t * 32 + jl], muL[qh * 32 + jl], u);
    uL[t] = u;
  }
  float nacc[32];
  #pragma unroll
  for (int b = 0; b < 32; ++b) nacc[b] = 0.0f;
  #pragma unroll
  for (int q = 0; q < 4; ++q) {
    int el = (q * 256 + t) * 4;       // 0..4095
    float4 g = *(const float4*)&LB[el];
    int i = el >> 5, jl = el & 31;
    const float* sb = R + i * 128 + qh * 32 + jl;
    #pragma unroll
    for (int b = 0; b < 32; ++b) {
      float4 sv = *(const float4*)&sb[(size_t)b * 16384];
      nacc[b] = fmaf(g.x, sv.x, nacc[b]);
      nacc[b] = fmaf(g.y, sv.y, nacc[b]);
      nacc[b] = fmaf(g.z, sv.z, nacc[b]);
      nacc[b] = fmaf(g.w, sv.w, nacc[b]);
    }
  }
  #pragma unroll
  for (int b = 0; b < 32; ++b) {
    float v = nacc[b];
    #pragma unroll
    for (int o = 32; o > 0; o >>= 1) v += __shfl_down(v, o, 64);
    nacc[b] = v;
  }
  if ((t & 63) == 0) {
    int w = t >> 6;
    #pragma unroll
    for (int b = 0; b < 32; ++b) redb[w][b] = nacc[b];
  }
  __syncthreads();
  if (t < 32) {
    float corr = 0.f;
    for (int i = 0; i < 128; ++i)
      corr = fmaf(uL[i], 256.0f * muL[i] - 2.0f * rbuf[t * 128 + i], corr);
    norm2h[(size_t)k * 128 + qh * 32 + t] =
        redb[0][t] + redb[1][t] + redb[2][t] + redb[3][t] + corr;
  }
}

// ---------------------------------------------------------------------------
// k8f (R18-verified): fused softmax weights + F accumulation. grid (64,4).
__global__ __launch_bounds__(256, 1) void k8f(const float* __restrict__ C,
                                              const float* __restrict__ E,
                                              const float* __restrict__ norm2h,
                                              const float* __restrict__ cnt,
                                              float* __restrict__ F) {
  int t = threadIdx.x;
  int e = blockIdx.x * 256 + t;
  int b0 = blockIdx.y * 8;
  __shared__ float wTl[128][8];
  __shared__ float redT[2];
  __shared__ float redN[2][8];
  __shared__ float redE[2][8];

  float nb[8];
  float cv = 0.f;
  if (t < 128) {
    int k = t;
    cv = cnt[k];
    #pragma unroll
    for (int j = 0; j < 8; ++j) {
      const float* nh = norm2h + (size_t)k * 128 + b0 + j;
      float n2 = nh[0] + nh[32] + nh[64] + nh[96];
      nb[j] = sqrtf(fmaxf(n2, 0.0f));
    }
    float tt = cv;
    float sn[8];
    #pragma unroll
    for (int j = 0; j < 8; ++j) sn[j] = nb[j];
    #pragma unroll
    for (int o = 32; o > 0; o >>= 1) {
      tt += __shfl_down(tt, o, 64);
      #pragma unroll
      for (int j = 0; j < 8; ++j) sn[j] += __shfl_down(sn[j], o, 64);
    }
    if ((t & 63) == 0) {
      redT[t >> 6] = tt;
      #pragma unroll
      for (int j = 0; j < 8; ++j) redN[t >> 6][j] = sn[j];
    }
  }
  __syncthreads();
  float exj[8];
  if (t < 128) {
    #pragma unroll
    for (int j = 0; j < 8; ++j) {
      float sumn = fmaxf(redN[0][j] + redN[1][j], 1e-30f);
      float nr = 10.0f * nb[j] / sumn;
      exj[j] = expf(-LAMBDA_S * nr);
    }
    float se[8];
    #pragma unroll
    for (int j = 0; j < 8; ++j) se[j] = exj[j];
    #pragma unroll
    for (int o = 32; o > 0; o >>= 1) {
      #pragma unroll
      for (int j = 0; j < 8; ++j) se[j] += __shfl_down(se[j], o, 64);
    }
    if ((t & 63) == 0) {
      #pragma unroll
      for (int j = 0; j < 8; ++j) redE[t >> 6][j] = se[j];
    }
  }
  __syncthreads();
  if (t < 128) {
    float total = redT[0] + redT[1];
    float bk = (cv != 0.0f) ? 1.0f : 0.0f;
    float gama = (total > 1e-6f) ? (cv / total) : 0.0f;
    #pragma unroll
    for (int j = 0; j < 8; ++j) {
      float sume = redE[0][j] + redE[1][j];
      float pi = (exj[j] / sume) * bk;
      wTl[t][j] = gama * pi;
    }
  }
  __syncthreads();

  float acc[8];
  float ev = E[e];
  #pragma unroll
  for (int b = 0; b < 8; ++b) acc[b] = ev;
  #pragma unroll 4
  for (int k = 0; k < 128; ++k) {
    float cval = C[(size_t)k * 16384 + e];
    #pragma unroll
    for (int b = 0; b < 8; ++b) acc[b] = fmaf(-wTl[k][b], cval, acc[b]);
  }
  #pragma unroll
  for (int b = 0; b < 8; ++b) F[(size_t)(b0 + b) * 16384 + e] = acc[b];
}

// ---------------------------------------------------------------------------
// k9 (R18-verified): out = xn + LR * F @ xn. grid 256, block 512 (acc[2][4]).
__global__ __launch_bounds__(512, 1) void k9_k(const float* __restrict__ F,
                                               const float* __restrict__ xn,
                                               float* __restrict__ out) {
  int bx = blockIdx.x;
  int b = bx >> 3, y = bx & 7;
  int mq = y >> 1, ih = y & 1;
  __shared__ __align__(16) float Ft[64 * 68];
  __shared__ __align__(16) float Xt[64 * 68];
  int t = threadIdx.x;
  int tx = t & 15, ty = t >> 4;   // ty 0..31
  float acc[2][4] = {};
  for (int jc = 0; jc < 128; jc += 64) {
    __syncthreads();
    #pragma unroll
    for (int q = 0; q < 2; ++q) {
      int e = q * 512 + t;
      int i = e >> 4, j4 = e & 15;
      *(float4*)&Ft[i * 68 + j4 * 4] =
          *(const float4*)&F[(size_t)b * 16384 + (ih * 64 + i) * 128 + jc + j4 * 4];
    }
    #pragma unroll
    for (int q = 0; q < 2; ++q) {
      int e = q * 512 + t;
      int jj = e >> 4, m4 = e & 15;
      *(float4*)&Xt[jj * 68 + m4 * 4] =
          *(const float4*)&xn[(size_t)b * (Nn * Mm) + (jc + jj) * Mm + mq * 64 + m4 * 4];
    }
    __syncthreads();
    for (int j4 = 0; j4 < 16; ++j4) {
      float4 fi[2], xm[4];
      #pragma unroll
      for (int r = 0; r < 2; ++r)
        fi[r] = *(const float4*)&Ft[(ty * 2 + r) * 68 + j4 * 4];
      #pragma unroll
      for (int r = 0; r < 4; ++r)
        xm[r] = *(const float4*)&Xt[(j4 * 4 + r) * 68 + tx * 4];
      #pragma unroll
      for (int qi = 0; qi < 2; ++qi) {
        #pragma unroll
        for (int qm = 0; qm < 4; ++qm) {
          float xv = ((const float*)&xm[0])[qm];
          acc[qi][qm] = fmaf(fi[qi].x, xv, acc[qi][qm]);
          xv = ((const float*)&xm[1])[qm];
          acc[qi][qm] = fmaf(fi[qi].y, xv, acc[qi][qm]);
          xv = ((const float*)&xm[2])[qm];
          acc[qi][qm] = fmaf(fi[qi].z, xv, acc[qi][qm]);
          xv = ((const float*)&xm[3])[qm];
          acc[qi][qm] = fmaf(fi[qi].w, xv, acc[qi][qm]);
        }
      }
    }
  }
  int i0 = ih * 64 + ty * 2, m0 = mq * 64 + tx * 4;
  #pragma unroll
  for (int qi = 0; qi < 2; ++qi) {
    float4 xv = *(const float4*)&xn[(size_t)b * (Nn * Mm) + (i0 + qi) * Mm + m0];
    float4 o;
    o.x = fmaf(LR, acc[qi][0], xv.x);
    o.y = fmaf(LR, acc[qi][1], xv.y);
    o.z = fmaf(LR, acc[qi][2], xv.z);
    o.w = fmaf(LR, acc[qi][3], xv.w);
    *(float4*)&out[(size_t)b * (Nn * Mm) + (i0 + qi) * Mm + m0] = o;
  }
}

// ---------------------------------------------------------------------------
extern "C" void kernel_launch(void* const* d_in, const int* in_sizes, int n_in,
                              void* d_out, int out_size, void* d_ws, size_t ws_size,
                              hipStream_t stream) {
  const float* x = (const float*)d_in[0];     // (32,128,256)
  const float* P = (const float*)d_in[1];     // (128,128,128) EC_proto
  const float* cnt = (const float*)d_in[2];   // (128,)
  float* out = (float*)d_out;

  float* ws = (float*)d_ws;
  float* xn = ws;                               // 1048576
  float* C = xn + 1048576;                      // 2113536 (c_k; slot 128 = e)
  float* R = C + 2113536;                       // 524288 (raw grams)
  float* norm2h = R + 524288;                   // 16384 (128 k x 4 quarters x 32 b)
  float* F = norm2h + 16384;                    // 524288
  float* Psum = F + 524288;                     // 16384
  float* rbuf = Psum + 16384;                   // 4096
  float* meanB = rbuf + 4096;                   // 128
  float* rstdB = meanB + 128;                   // 128
  size_t need_bytes = (size_t)((rstdB + 128) - ws) * sizeof(float);
  if (ws_size < need_bytes) return;  // ~17 MB required

  hipLaunchKernelGGL(kPre, dim3(64), dim3(256), 0, stream, P, Psum);
  hipLaunchKernelGGL(kBig, dim3(321), dim3(512), 0, stream, P, Psum, cnt, C, x,
                     R, rbuf, meanB, rstdB, xn);
  hipLaunchKernelGGL(kGN, dim3(512), dim3(256), 0, stream, C, R, rbuf, meanB,
                     rstdB, norm2h);
  hipLaunchKernelGGL(k8f, dim3(64, 4), dim3(256), 0, stream, C,
                     C + (size_t)128 * 16384, norm2h, cnt, F);
  hipLaunchKernelGGL(k9_k, dim3(256), dim3(512), 0, stream, F, xn, out);
}

// Round 13
// 158.810 us; speedup vs baseline: 1.0206x; 1.0206x over previous
//
#include <hip/hip_runtime.h>
#include <math.h>

// Problem constants (B,K,N,M) = (32,128,128,256)
#define Bb 32
#define Kk 128
#define Nn 128
#define Mm 256
#define EPS2 0.01f      // EPSILON^2
#define LAMBDA_S 0.1f
#define LR 0.01f
#define BN_EPS_C 1e-5f

#define SWZ(c) (((c) & 14) | (((c) & 1) << 4) | (((c) >> 4) & 1))

__device__ __forceinline__ float readlane_f(float v, int lane) {
  return __int_as_float(__builtin_amdgcn_readlane(__float_as_int(v), lane));
}

// ---------------------------------------------------------------------------
// kA: fused BatchNorm (blocks 0..127, x kept in regs) + Psum (blocks 128..191).
__global__ void kA_bn_psum(const float* __restrict__ x, const float* __restrict__ P,
                           float* __restrict__ xn, float* __restrict__ Psum) {
  int t = threadIdx.x;
  if (blockIdx.x < 128) {
    int n = blockIdx.x;
    float v[32];
    float s = 0.f, s2 = 0.f;
    #pragma unroll
    for (int b = 0; b < Bb; ++b) {
      v[b] = x[(size_t)b * (Nn * Mm) + n * Mm + t];
      s += v[b];
      s2 += v[b] * v[b];
    }
    #pragma unroll
    for (int o = 32; o > 0; o >>= 1) {
      s += __shfl_down(s, o, 64);
      s2 += __shfl_down(s2, o, 64);
    }
    __shared__ float rs[4], rs2[4];
    if ((t & 63) == 0) { rs[t >> 6] = s; rs2[t >> 6] = s2; }
    __syncthreads();
    float S = rs[0] + rs[1] + rs[2] + rs[3];
    float S2 = rs2[0] + rs2[1] + rs2[2] + rs2[3];
    float mean = S * (1.0f / (Bb * Mm));
    float var = S2 * (1.0f / (Bb * Mm)) - mean * mean;
    float rstd = 1.0f / sqrtf(var + BN_EPS_C);
    #pragma unroll
    for (int b = 0; b < Bb; ++b)
      xn[(size_t)b * (Nn * Mm) + n * Mm + t] = (v[b] - mean) * rstd;
  } else {
    int e = (blockIdx.x - 128) * 256 + t;
    float s = 0.f;
    #pragma unroll 8
    for (int k = 0; k < Kk; ++k) s += P[(size_t)k * 16384 + e];
    Psum[e] = s;
  }
}

// ---------------------------------------------------------------------------
// k3S (R11-proven, untouched): blocks 0..128 = blocked GJ inverse, 512 thr
// (8 waves = 2/SIMD), each thread a 4x8 tile. blocks 129..192 = S_b.
__global__ __launch_bounds__(512, 1) void k3S(
    const float* __restrict__ P, const float* __restrict__ Psum,
    const float* __restrict__ cnt, float* __restrict__ C,
    const float* __restrict__ xn, float* __restrict__ S) {
  __shared__ __align__(16) float LB[8448];
  int bx = blockIdx.x;
  int t = threadIdx.x;

  if (bx < 129) {
    float* Mt = LB;            // 16*132 = 2112
    float* Rb = LB + 2112;     // 16*128 = 2048
    float* redc = LB + 4160;   // 8
    int mat = bx;
    int tx = t & 15;           // col group (8 cols)
    int wy = t >> 4;           // row group (4 rows), 0..31

    float cv = cnt[t & 127];
    float sr = cv;
    #pragma unroll
    for (int o = 32; o > 0; o >>= 1) sr += __shfl_down(sr, o, 64);
    if ((t & 63) == 0) redc[t >> 6] = sr;
    __syncthreads();
    float total = redc[0] + redc[1];
    bool has = total > 1e-6f;
    float av;
    if (mat < 128) {
      float c = cnt[mat];
      float bk = (c != 0.0f) ? 1.0f : 0.0f;
      float cfix = c + (1.0f - bk);
      av = (float)Nn / (cfix * EPS2) * bk;
    } else {
      av = has ? ((float)Nn / (EPS2 * total)) : 0.0f;
    }
    const float* src = (mat < 128) ? (P + (size_t)mat * 16384) : Psum;

    float a[4][8];
    #pragma unroll
    for (int i = 0; i < 4; ++i) {
      int row = wy * 4 + i;
      float4 p0 = *(const float4*)&src[row * 128 + tx * 8];
      float4 p1 = *(const float4*)&src[row * 128 + tx * 8 + 4];
      a[i][0] = av * p0.x; a[i][1] = av * p0.y; a[i][2] = av * p0.z; a[i][3] = av * p0.w;
      a[i][4] = av * p1.x; a[i][5] = av * p1.y; a[i][6] = av * p1.z; a[i][7] = av * p1.w;
      if (tx == (wy >> 1)) a[i][(wy & 1) * 4 + i] += 1.0f;
    }

    for (int kb = 0; kb < 8; ++kb) {
      int k0 = kb * 16;
      if ((wy >> 2) == kb) {          // R dump (panel rows, swizzled)
        int d = wy & 3;
        #pragma unroll
        for (int i = 0; i < 4; ++i) {
          *(float4*)&Rb[(d * 4 + i) * 128 + SWZ(2 * tx) * 4] =
              make_float4(a[i][0], a[i][1], a[i][2], a[i][3]);
          *(float4*)&Rb[(d * 4 + i) * 128 + SWZ(2 * tx + 1) * 4] =
              make_float4(a[i][4], a[i][5], a[i][6], a[i][7]);
        }
      }
      if ((tx >> 1) == kb) {          // M dump (panel cols, transposed)
        int dh = tx & 1;
        #pragma unroll
        for (int i = 0; i < 4; ++i)
          #pragma unroll
          for (int j = 0; j < 8; ++j)
            Mt[(dh * 8 + j) * 132 + wy * 4 + i] = a[i][j];
      }
      __syncthreads();

      if (t < 64) {                   // wave 0 factors the 128x16 panel
        int l = t;
        float m[2][16];
        #pragma unroll
        for (int d = 0; d < 2; ++d)
          #pragma unroll
          for (int j = 0; j < 16; ++j)
            m[d][j] = Mt[j * 132 + 2 * l + d];
        #pragma unroll
        for (int q = 0; q < 16; ++q) {
          int lq = (k0 + q) >> 1;     // wave-uniform owner lane
          float pr[16];
          #pragma unroll
          for (int j = 0; j < 16; ++j) pr[j] = readlane_f(m[q & 1][j], lq);
          float piv = pr[q];
          float r0 = __builtin_amdgcn_rcpf(piv);
          float pinv = r0 * (2.0f - piv * r0);   // Newton -> ~fp32-exact
          #pragma unroll
          for (int d = 0; d < 2; ++d) {
            float f = m[d][q];
            bool isp = (2 * l + d == k0 + q);
            float g = isp ? (1.0f - pinv) : f * pinv;
            #pragma unroll
            for (int j = 0; j < 16; ++j) m[d][j] = fmaf(-g, pr[j], m[d][j]);
            m[d][q] = isp ? pinv : -g;
          }
        }
        #pragma unroll
        for (int d = 0; d < 2; ++d)
          #pragma unroll
          for (int j = 0; j < 16; ++j)
            Mt[j * 132 + 2 * l + d] = m[d][j];
      }
      __syncthreads();

      if ((wy >> 2) == kb) {          // panel rows restart acc
        #pragma unroll
        for (int i = 0; i < 4; ++i)
          #pragma unroll
          for (int j = 0; j < 8; ++j) a[i][j] = 0.0f;
      }
      #pragma unroll
      for (int q = 0; q < 16; ++q) {
        float4 m0 = *(const float4*)&Mt[q * 132 + wy * 4];
        float4 r0 = *(const float4*)&Rb[q * 128 + SWZ(2 * tx) * 4];
        float4 r1 = *(const float4*)&Rb[q * 128 + SWZ(2 * tx + 1) * 4];
        float mq[4] = {m0.x, m0.y, m0.z, m0.w};
        float rq[8] = {r0.x, r0.y, r0.z, r0.w, r1.x, r1.y, r1.z, r1.w};
        #pragma unroll
        for (int i = 0; i < 4; ++i)
          #pragma unroll
          for (int j = 0; j < 8; ++j)
            a[i][j] = fmaf(mq[i], rq[j], a[i][j]);
      }
      if ((tx >> 1) == kb) {          // panel cols reload M
        int dh = tx & 1;
        #pragma unroll
        for (int j = 0; j < 8; ++j) {
          float4 v0 = *(const float4*)&Mt[(dh * 8 + j) * 132 + wy * 4];
          a[0][j] = v0.x; a[1][j] = v0.y; a[2][j] = v0.z; a[3][j] = v0.w;
        }
      }
      __syncthreads();
    }

    float* dst = C + (size_t)mat * 16384;
    #pragma unroll
    for (int i = 0; i < 4; ++i) {
      int row = wy * 4 + i;
      float4 v0 = make_float4(av * a[i][0], av * a[i][1], av * a[i][2], av * a[i][3]);
      float4 v1 = make_float4(av * a[i][4], av * a[i][5], av * a[i][6], av * a[i][7]);
      *(float4*)&dst[row * 128 + tx * 8] = v0;
      *(float4*)&dst[row * 128 + tx * 8 + 4] = v1;
    }
  } else {
    // ---- S branch: S_b = xn_b xn_b^T (b = bxx>>1, col-half = bxx&1) ----
    int bxx = bx - 129;
    int b = bxx >> 1;
    int jbase = (bxx & 1) * 64;
    float* X = LB;  // 128*65 = 8320 floats
    int tx = t & 15, wy = t >> 4;   // wy 0..31
    float acc[4][4] = {};
    for (int mc = 0; mc < Mm; mc += 64) {
      __syncthreads();
      #pragma unroll
      for (int c = 0; c < 16; ++c) {   // all 512 threads stage
        int e = c * 512 + t;
        int i = e >> 6, mm = e & 63;
        X[i * 65 + mm] = xn[(size_t)b * (Nn * Mm) + i * Mm + mc + mm];
      }
      __syncthreads();
      for (int mm = 0; mm < 64; ++mm) {
        float ai[4], bj[4];
        #pragma unroll
        for (int q = 0; q < 4; ++q) ai[q] = X[(wy * 4 + q) * 65 + mm];
        #pragma unroll
        for (int q = 0; q < 4; ++q) bj[q] = X[(jbase + tx * 4 + q) * 65 + mm];
        #pragma unroll
        for (int qi = 0; qi < 4; ++qi)
          #pragma unroll
          for (int qj = 0; qj < 4; ++qj)
            acc[qi][qj] = fmaf(ai[qi], bj[qj], acc[qi][qj]);
      }
    }
    float* dst = S + (size_t)b * 16384;
    #pragma unroll
    for (int qi = 0; qi < 4; ++qi) {
      float4 v = make_float4(acc[qi][0], acc[qi][1], acc[qi][2], acc[qi][3]);
      *(float4*)&dst[(wy * 4 + qi) * 128 + jbase + tx * 4] = v;
    }
  }
}

// ---------------------------------------------------------------------------
// kGN (R14-proven): grid 512 = (k, j-quarter). 2 blocks/CU co-resident.
__global__ __launch_bounds__(256, 1) void kGN(const float* __restrict__ C,
                                              const float* __restrict__ S,
                                              float* __restrict__ norm2h) {
  __shared__ __align__(16) float LB[128 * 128];  // 64 KB
  __shared__ float redb[4][32];
  int k = blockIdx.x >> 2, qh = blockIdx.x & 3;
  int t = threadIdx.x;
  const float* src = C + (size_t)k * 16384;
  for (int c = 0; c < 64; ++c) LB[c * 256 + t] = src[c * 256 + t];
  __syncthreads();
  int tx = t & 15, ty = t >> 4;
  int i0 = ty * 8, j0 = qh * 32 + tx * 2;
  float acc[8][2] = {};
  #pragma unroll 2
  for (int l = 0; l < 128; ++l) {
    float ai[8];
    *(float4*)&ai[0] = *(const float4*)&LB[l * 128 + i0];
    *(float4*)&ai[4] = *(const float4*)&LB[l * 128 + i0 + 4];
    float2 bj = *(const float2*)&LB[l * 128 + j0];
    #pragma unroll
    for (int qi = 0; qi < 8; ++qi) {
      acc[qi][0] = fmaf(ai[qi], bj.x, acc[qi][0]);
      acc[qi][1] = fmaf(ai[qi], bj.y, acc[qi][1]);
    }
  }
  __syncthreads();
  #pragma unroll
  for (int qi = 0; qi < 8; ++qi)
    *(float2*)&LB[(i0 + qi) * 32 + tx * 2] = make_float2(acc[qi][0], acc[qi][1]);
  __syncthreads();
  float nacc[32];
  #pragma unroll
  for (int b = 0; b < 32; ++b) nacc[b] = 0.0f;
  #pragma unroll
  for (int q = 0; q < 4; ++q) {
    int el = (q * 256 + t) * 4;       // 0..4095
    float4 g = *(const float4*)&LB[el];
    int i = el >> 5, jl = el & 31;
    const float* sb = S + i * 128 + qh * 32 + jl;
    #pragma unroll
    for (int b = 0; b < 32; ++b) {
      float4 sv = *(const float4*)&sb[(size_t)b * 16384];
      nacc[b] = fmaf(g.x, sv.x, nacc[b]);
      nacc[b] = fmaf(g.y, sv.y, nacc[b]);
      nacc[b] = fmaf(g.z, sv.z, nacc[b]);
      nacc[b] = fmaf(g.w, sv.w, nacc[b]);
    }
  }
  #pragma unroll
  for (int b = 0; b < 32; ++b) {
    float v = nacc[b];
    #pragma unroll
    for (int o = 32; o > 0; o >>= 1) v += __shfl_down(v, o, 64);
    nacc[b] = v;
  }
  if ((t & 63) == 0) {
    int w = t >> 6;
    #pragma unroll
    for (int b = 0; b < 32; ++b) redb[w][b] = nacc[b];
  }
  __syncthreads();
  if (t < 32)
    norm2h[(size_t)k * 128 + qh * 32 + t] =
        redb[0][t] + redb[1][t] + redb[2][t] + redb[3][t];
}

// ---------------------------------------------------------------------------
// k8f (R18-verified): fused softmax weights + F accumulation. grid (64,4).
__global__ __launch_bounds__(256, 1) void k8f(const float* __restrict__ C,
                                              const float* __restrict__ E,
                                              const float* __restrict__ norm2h,
                                              const float* __restrict__ cnt,
                                              float* __restrict__ F) {
  int t = threadIdx.x;
  int e = blockIdx.x * 256 + t;
  int b0 = blockIdx.y * 8;
  __shared__ float wTl[128][8];
  __shared__ float redT[2];
  __shared__ float redN[2][8];
  __shared__ float redE[2][8];

  float nb[8];
  float cv = 0.f;
  if (t < 128) {
    int k = t;
    cv = cnt[k];
    #pragma unroll
    for (int j = 0; j < 8; ++j) {
      const float* nh = norm2h + (size_t)k * 128 + b0 + j;
      float n2 = nh[0] + nh[32] + nh[64] + nh[96];
      nb[j] = sqrtf(fmaxf(n2, 0.0f));
    }
    float tt = cv;
    float sn[8];
    #pragma unroll
    for (int j = 0; j < 8; ++j) sn[j] = nb[j];
    #pragma unroll
    for (int o = 32; o > 0; o >>= 1) {
      tt += __shfl_down(tt, o, 64);
      #pragma unroll
      for (int j = 0; j < 8; ++j) sn[j] += __shfl_down(sn[j], o, 64);
    }
    if ((t & 63) == 0) {
      redT[t >> 6] = tt;
      #pragma unroll
      for (int j = 0; j < 8; ++j) redN[t >> 6][j] = sn[j];
    }
  }
  __syncthreads();
  float exj[8];
  if (t < 128) {
    #pragma unroll
    for (int j = 0; j < 8; ++j) {
      float sumn = fmaxf(redN[0][j] + redN[1][j], 1e-30f);
      float nr = 10.0f * nb[j] / sumn;
      exj[j] = expf(-LAMBDA_S * nr);
    }
    float se[8];
    #pragma unroll
    for (int j = 0; j < 8; ++j) se[j] = exj[j];
    #pragma unroll
    for (int o = 32; o > 0; o >>= 1) {
      #pragma unroll
      for (int j = 0; j < 8; ++j) se[j] += __shfl_down(se[j], o, 64);
    }
    if ((t & 63) == 0) {
      #pragma unroll
      for (int j = 0; j < 8; ++j) redE[t >> 6][j] = se[j];
    }
  }
  __syncthreads();
  if (t < 128) {
    float total = redT[0] + redT[1];
    float bk = (cv != 0.0f) ? 1.0f : 0.0f;
    float gama = (total > 1e-6f) ? (cv / total) : 0.0f;
    #pragma unroll
    for (int j = 0; j < 8; ++j) {
      float sume = redE[0][j] + redE[1][j];
      float pi = (exj[j] / sume) * bk;
      wTl[t][j] = gama * pi;
    }
  }
  __syncthreads();

  float acc[8];
  float ev = E[e];
  #pragma unroll
  for (int b = 0; b < 8; ++b) acc[b] = ev;
  #pragma unroll 4
  for (int k = 0; k < 128; ++k) {
    float cval = C[(size_t)k * 16384 + e];
    #pragma unroll
    for (int b = 0; b < 8; ++b) acc[b] = fmaf(-wTl[k][b], cval, acc[b]);
  }
  #pragma unroll
  for (int b = 0; b < 8; ++b) F[(size_t)(b0 + b) * 16384 + e] = acc[b];
}

// ---------------------------------------------------------------------------
// k9 (R18-verified): out = xn + LR * F @ xn. grid 256, block 512 (acc[2][4]).
__global__ __launch_bounds__(512, 1) void k9_k(const float* __restrict__ F,
                                               const float* __restrict__ xn,
                                               float* __restrict__ out) {
  int bx = blockIdx.x;
  int b = bx >> 3, y = bx & 7;
  int mq = y >> 1, ih = y & 1;
  __shared__ __align__(16) float Ft[64 * 68];
  __shared__ __align__(16) float Xt[64 * 68];
  int t = threadIdx.x;
  int tx = t & 15, ty = t >> 4;   // ty 0..31
  float acc[2][4] = {};
  for (int jc = 0; jc < 128; jc += 64) {
    __syncthreads();
    #pragma unroll
    for (int q = 0; q < 2; ++q) {
      int e = q * 512 + t;
      int i = e >> 4, j4 = e & 15;
      *(float4*)&Ft[i * 68 + j4 * 4] =
          *(const float4*)&F[(size_t)b * 16384 + (ih * 64 + i) * 128 + jc + j4 * 4];
    }
    #pragma unroll
    for (int q = 0; q < 2; ++q) {
      int e = q * 512 + t;
      int jj = e >> 4, m4 = e & 15;
      *(float4*)&Xt[jj * 68 + m4 * 4] =
          *(const float4*)&xn[(size_t)b * (Nn * Mm) + (jc + jj) * Mm + mq * 64 + m4 * 4];
    }
    __syncthreads();
    for (int j4 = 0; j4 < 16; ++j4) {
      float4 fi[2], xm[4];
      #pragma unroll
      for (int r = 0; r < 2; ++r)
        fi[r] = *(const float4*)&Ft[(ty * 2 + r) * 68 + j4 * 4];
      #pragma unroll
      for (int r = 0; r < 4; ++r)
        xm[r] = *(const float4*)&Xt[(j4 * 4 + r) * 68 + tx * 4];
      #pragma unroll
      for (int qi = 0; qi < 2; ++qi) {
        #pragma unroll
        for (int qm = 0; qm < 4; ++qm) {
          float xv = ((const float*)&xm[0])[qm];
          acc[qi][qm] = fmaf(fi[qi].x, xv, acc[qi][qm]);
          xv = ((const float*)&xm[1])[qm];
          acc[qi][qm] = fmaf(fi[qi].y, xv, acc[qi][qm]);
          xv = ((const float*)&xm[2])[qm];
          acc[qi][qm] = fmaf(fi[qi].z, xv, acc[qi][qm]);
          xv = ((const float*)&xm[3])[qm];
          acc[qi][qm] = fmaf(fi[qi].w, xv, acc[qi][qm]);
        }
      }
    }
  }
  int i0 = ih * 64 + ty * 2, m0 = mq * 64 + tx * 4;
  #pragma unroll
  for (int qi = 0; qi < 2; ++qi) {
    float4 xv = *(const float4*)&xn[(size_t)b * (Nn * Mm) + (i0 + qi) * Mm + m0];
    float4 o;
    o.x = fmaf(LR, acc[qi][0], xv.x);
    o.y = fmaf(LR, acc[qi][1], xv.y);
    o.z = fmaf(LR, acc[qi][2], xv.z);
    o.w = fmaf(LR, acc[qi][3], xv.w);
    *(float4*)&out[(size_t)b * (Nn * Mm) + (i0 + qi) * Mm + m0] = o;
  }
}

// ---------------------------------------------------------------------------
extern "C" void kernel_launch(void* const* d_in, const int* in_sizes, int n_in,
                              void* d_out, int out_size, void* d_ws, size_t ws_size,
                              hipStream_t stream) {
  const float* x = (const float*)d_in[0];     // (32,128,256)
  const float* P = (const float*)d_in[1];     // (128,128,128) EC_proto
  const float* cnt = (const float*)d_in[2];   // (128,)
  float* out = (float*)d_out;

  float* ws = (float*)d_ws;
  float* xn = ws;                               // 1048576
  float* C = xn + 1048576;                      // 129*16384 (c_k; slot 128 = e)
  float* S = C + 2113536;                       // 524288
  float* norm2h = S + 524288;                   // 16384 (128 k x 4 quarters x 32 b)
  float* F = norm2h + 16384;                    // 524288
  float* Psum = F + 524288;                     // 16384
  size_t need_bytes = (size_t)((Psum + 16384) - ws) * sizeof(float);
  if (ws_size < need_bytes) return;  // ~17 MB required

  hipLaunchKernelGGL(kA_bn_psum, dim3(192), dim3(256), 0, stream, x, P, xn, Psum);
  hipLaunchKernelGGL(k3S, dim3(193), dim3(512), 0, stream, P, Psum, cnt, C, xn, S);
  hipLaunchKernelGGL(kGN, dim3(512), dim3(256), 0, stream, C, S, norm2h);
  hipLaunchKernelGGL(k8f, dim3(64, 4), dim3(256), 0, stream, C,
                     C + (size_t)128 * 16384, norm2h, cnt, F);
  hipLaunchKernelGGL(k9_k, dim3(256), dim3(512), 0, stream, F, xn, out);
}